// Round 4
// baseline (105933.337 us; speedup 1.0000x reference)
//
#include <hip/hip_runtime.h>
#include <math.h>

typedef float f4 __attribute__((ext_vector_type(4)));
typedef _Float16 f16x8 __attribute__((ext_vector_type(8)));
typedef int i4 __attribute__((ext_vector_type(4)));

#define Hdim 2048
#define Bdim 256
#define Tdim 512
#define Odim 14
#define G3   6144   // 3*Hdim

// ---------------------------------------------------------------------------
// Prep kernels (once per launch)
// ---------------------------------------------------------------------------

// Gtable[c][row], c in 0..14: gi row for one-hot input c (c==14 -> dead, x=0)
__global__ void prep_gtable(const float* __restrict__ b_ih,
                            const float* __restrict__ W_ih,
                            float* __restrict__ Gt) {
    int idx = blockIdx.x * 256 + threadIdx.x;
    if (idx >= 15 * G3) return;
    int c = idx / G3, row = idx % G3;
    float v = b_ih[row];
    if (c < Odim) v += W_ih[row * Odim + c];
    Gt[idx] = v;
}

// W_hh (6144x2048 f32) -> hi/lo fp16 frag-major with GATE-TRIPLE tile order.
// Original row n = g*2048 + j.  ntp = (j>>5)*6 + ((j>>4)&1)*3 + g, col = j&15.
// Layout: [ntp][kb][lane][8], k = kb*32 + (lane>>4)*8 + e, lane = col + 16*q.
__global__ void prep_Bpack(const float* __restrict__ W,
                           _Float16* __restrict__ Bh, _Float16* __restrict__ Bl) {
    int idx = blockIdx.x * 256 + threadIdx.x;  // 6144*256
    int n = idx >> 8, kc = idx & 255;
    int g = n >> 11, j = n & 2047;
    int ntp = (j >> 5) * 6 + ((j >> 4) & 1) * 3 + g;
    const float* src = W + (size_t)n * Hdim + kc * 8;
    int kb = kc >> 2, q = kc & 3;
    int lane = (j & 15) + 16 * q;
    f16x8 vh, vl;
    #pragma unroll
    for (int e = 0; e < 8; ++e) {
        float w = src[e];
        _Float16 h = (_Float16)w;
        vh[e] = h;
        vl[e] = (_Float16)(w - (float)h);
    }
    size_t off = (((size_t)ntp * 64 + kb) * 64 + lane) * 8;
    *(f16x8*)(Bh + off) = vh;
    *(f16x8*)(Bl + off) = vl;
}

// enc_hidden (256x2048 f32) -> hi/lo fp16 frag-major: [mt][kb][lane][8]
__global__ void prep_A0(const float* __restrict__ h0,
                        _Float16* __restrict__ Ah, _Float16* __restrict__ Al) {
    int idx = blockIdx.x * 256 + threadIdx.x;  // 256*256
    int m = idx >> 8, kc = idx & 255;
    const float* src = h0 + (size_t)m * Hdim + kc * 8;
    int kb = kc >> 2, q = kc & 3;
    int lane = (m & 15) + 16 * q;
    int mt = m >> 4;
    f16x8 vh, vl;
    #pragma unroll
    for (int e = 0; e < 8; ++e) {
        float w = src[e];
        _Float16 h = (_Float16)w;
        vh[e] = h;
        vl[e] = (_Float16)(w - (float)h);
    }
    size_t off = (((size_t)mt * 64 + kb) * 64 + lane) * 8;
    *(f16x8*)(Ah + off) = vh;
    *(f16x8*)(Al + off) = vl;
}

// zero counters / logit accumulator (ws is poison-filled before every call)
__global__ void zero_misc(int* __restrict__ cnt, int* __restrict__ lastc,
                          float* __restrict__ Llog) {
    int i = blockIdx.x * 256 + threadIdx.x;
    if (i < Tdim * 64) cnt[i] = 0;
    if (i < Tdim) lastc[i] = 0;
    if (i < Bdim * Odim) Llog[i] = 0.f;
}

// ---------------------------------------------------------------------------
// One GRU step, fully fused. grid (64 gate-triple N-tiles, 4 K-slices), 512 thr.
// Phase A: 3-product hi/lo fp16 MFMA partial GEMM -> Cpart.
// Phase B (4th wg per tile): K-reduce + gates + h update + next A-pack +
//   partial logits (atomicAdd).
// Phase C (64th reducer): argmax + log_softmax + topi + lp.
// Fire-and-forget counters; __threadfence() release/acquire; no spins.
// ---------------------------------------------------------------------------
__global__ __launch_bounds__(512, 1)
void step_kernel(const _Float16* __restrict__ Ah, const _Float16* __restrict__ Al,
                 const _Float16* __restrict__ Bh, const _Float16* __restrict__ Bl,
                 float* __restrict__ Cpart,
                 const float* __restrict__ hprev, float* __restrict__ hnew,
                 const float* __restrict__ Gt, const float* __restrict__ target,
                 const float* __restrict__ W_ih, const float* __restrict__ b_ih,
                 const float* __restrict__ b_hh,
                 const float* __restrict__ W_out, const float* __restrict__ b_out,
                 _Float16* __restrict__ nAh, _Float16* __restrict__ nAl,
                 const int* __restrict__ topi_in, int* __restrict__ topi_out,
                 float* __restrict__ lp, float* __restrict__ hfin,
                 int* __restrict__ cnt, int* __restrict__ lastc,
                 float* __restrict__ Llog, int t) {
    __shared__ _Float16 sB[2][24576];   // per buf: hi 12288 | lo 12288 halves
    __shared__ float s_wout[Odim][32];
    __shared__ int s_sel[256];
    __shared__ unsigned long long s_m[4];
    __shared__ int s_old;

    const int tid = threadIdx.x;
    const int wave = tid >> 6, lane = tid & 63;
    const int mq = wave & 3, nh = wave >> 2;   // M-quarter, N-half
    const int nt = blockIdx.x;                 // gate-triple tile (32 j-cols)
    const int kb0 = blockIdx.y * 16;           // K-slice: 16 kb-blocks = 512 k

    f4 acc[4][3];
    #pragma unroll
    for (int mf = 0; mf < 4; ++mf)
        #pragma unroll
        for (int nf = 0; nf < 3; ++nf) acc[mf][nf] = (f4)0.f;

    i4 rh[3], rl[3];
    // stage chunk 0 (4 kb-blocks, 6 frag-rows, hi+lo)
    #pragma unroll
    for (int i = 0; i < 3; ++i) {
        int e = i * 512 + tid, blk = e >> 6, l = e & 63;
        int ntl = blk >> 2, kbl = blk & 3;
        size_t so = (((size_t)(nt * 6 + ntl) * 64) + kb0 + kbl) * 512 + l * 8;
        rh[i] = *(const i4*)(Bh + so);
        rl[i] = *(const i4*)(Bl + so);
    }
    #pragma unroll
    for (int i = 0; i < 3; ++i) {
        int e = i * 512 + tid;
        ((i4*)sB[0])[e] = rh[i];
        ((i4*)sB[0])[1536 + e] = rl[i];
    }
    __syncthreads();

    for (int c = 0; c < 4; ++c) {
        const int buf = c & 1;
        if (c < 3) {   // register-prefetch next chunk
            #pragma unroll
            for (int i = 0; i < 3; ++i) {
                int e = i * 512 + tid, blk = e >> 6, l = e & 63;
                int ntl = blk >> 2, kbl = blk & 3;
                size_t so = (((size_t)(nt * 6 + ntl) * 64) + kb0 + (c + 1) * 4 + kbl) * 512 + l * 8;
                rh[i] = *(const i4*)(Bh + so);
                rl[i] = *(const i4*)(Bl + so);
            }
        }
        #pragma unroll
        for (int kbl = 0; kbl < 4; ++kbl) {
            const int kb = kb0 + c * 4 + kbl;
            f16x8 a_h[4], a_l[4], b_h[3], b_l[3];
            #pragma unroll
            for (int mf = 0; mf < 4; ++mf) {
                size_t off = (((size_t)(mq * 4 + mf) * 64 + kb) * 64 + lane) * 8;
                a_h[mf] = *(const f16x8*)(Ah + off);
                a_l[mf] = *(const f16x8*)(Al + off);
            }
            #pragma unroll
            for (int nf = 0; nf < 3; ++nf) {
                int base = ((nh * 3 + nf) * 4 + kbl) * 512 + lane * 8;
                b_h[nf] = *(const f16x8*)(&sB[buf][base]);
                b_l[nf] = *(const f16x8*)(&sB[buf][12288 + base]);
            }
            #pragma unroll
            for (int mf = 0; mf < 4; ++mf)
                #pragma unroll
                for (int nf = 0; nf < 3; ++nf) {
                    acc[mf][nf] = __builtin_amdgcn_mfma_f32_16x16x32_f16(
                        a_h[mf], b_h[nf], acc[mf][nf], 0, 0, 0);
                    acc[mf][nf] = __builtin_amdgcn_mfma_f32_16x16x32_f16(
                        a_h[mf], b_l[nf], acc[mf][nf], 0, 0, 0);
                    acc[mf][nf] = __builtin_amdgcn_mfma_f32_16x16x32_f16(
                        a_l[mf], b_h[nf], acc[mf][nf], 0, 0, 0);
                }
        }
        if (c < 3) {
            #pragma unroll
            for (int i = 0; i < 3; ++i) {
                int e = i * 512 + tid;
                ((i4*)sB[buf ^ 1])[e] = rh[i];
                ((i4*)sB[buf ^ 1])[1536 + e] = rl[i];
            }
            __syncthreads();
        }
    }

    // store partials (C/D frag: col=lane&15, row=(lane>>4)*4+q)
    {
        const size_t cb = (size_t)blockIdx.y * Bdim * G3;
        #pragma unroll
        for (int mf = 0; mf < 4; ++mf) {
            int mr = mq * 64 + mf * 16 + (lane >> 4) * 4;
            #pragma unroll
            for (int nf = 0; nf < 3; ++nf) {
                int col = nt * 96 + (nh * 3 + nf) * 16 + (lane & 15);
                #pragma unroll
                for (int q = 0; q < 4; ++q)
                    Cpart[cb + (size_t)(mr + q) * G3 + col] = acc[mf][nf][q];
            }
        }
    }

    // ---- tile completion counter ----
    __threadfence();
    if (tid == 0) s_old = atomicAdd(&cnt[nt], 1);
    __syncthreads();
    if (s_old != 3) return;          // not the last K-slice wg for this tile
    __threadfence();                 // acquire: see all 4 slices' Cpart

    // ---- Phase B: reducer for tile nt (32 j-cols x 256 batch) ----
    if (tid < Odim * 32) {
        int o = tid >> 5, cc = tid & 31;
        s_wout[o][cc] = W_out[(size_t)o * Hdim + nt * 32 + cc];
    }
    if (t > 0 && tid < 256) {
        int tp = topi_in[tid];
        unsigned long long m = __ballot(tp == (Odim - 1));
        if ((tid & 63) == 0) s_m[tid >> 6] = m;
    }
    __syncthreads();
    if (t > 0 && tid < 256) {
        int bw = tid >> 6, bl_ = tid & 63;
        unsigned long long le =
            s_m[bw] & ((bl_ == 63) ? ~0ULL : ((1ULL << (bl_ + 1)) - 1ULL));
        bool dead = (le != 0ULL);
        #pragma unroll
        for (int w2 = 0; w2 < 3; ++w2)
            if (w2 < bw) dead = dead || (s_m[w2] != 0ULL);
        s_sel[tid] = dead ? Odim : topi_in[tid];
    }
    __syncthreads();

    const int b = tid >> 1, jg = tid & 1;
    const int j0g = nt * 32 + jg * 16;

    float gin[3][16];
    if (t == 0) {   // on-the-fly gi from relu(x0) @ W_ih^T + b_ih
        float x0[Odim];
        #pragma unroll
        for (int o = 0; o < Odim; ++o)
            x0[o] = fmaxf(target[(size_t)b * (Tdim * Odim) + o], 0.f);
        #pragma unroll
        for (int g = 0; g < 3; ++g)
            #pragma unroll
            for (int cc = 0; cc < 16; ++cc) {
                int row = g * Hdim + j0g + cc;
                const float* wr = W_ih + (size_t)row * Odim;
                float s = b_ih[row];
                #pragma unroll
                for (int o = 0; o < Odim; ++o) s = fmaf(x0[o], wr[o], s);
                gin[g][cc] = s;
            }
    } else {
        const float* gp = Gt + (size_t)s_sel[b] * G3;
        #pragma unroll
        for (int g = 0; g < 3; ++g)
            #pragma unroll
            for (int v = 0; v < 4; ++v) {
                f4 s = *(const f4*)(gp + g * Hdim + j0g + v * 4);
                #pragma unroll
                for (int cc = 0; cc < 4; ++cc) gin[g][v * 4 + cc] = s[cc];
            }
    }

    float gs[3][16];
    #pragma unroll
    for (int g = 0; g < 3; ++g)
        #pragma unroll
        for (int v = 0; v < 4; ++v) {
            f4 s = *(const f4*)(b_hh + g * Hdim + j0g + v * 4);
            #pragma unroll
            for (int ks = 0; ks < 4; ++ks)
                s += *(const f4*)(Cpart + ((size_t)ks * Bdim + b) * G3 +
                                  nt * 96 + jg * 48 + g * 16 + v * 4);
            #pragma unroll
            for (int cc = 0; cc < 4; ++cc) gs[g][v * 4 + cc] = s[cc];
        }

    float hn[16];
    #pragma unroll
    for (int v = 0; v < 4; ++v) {
        f4 hp = *(const f4*)(hprev + (size_t)b * Hdim + j0g + v * 4);
        #pragma unroll
        for (int cc = 0; cc < 4; ++cc) {
            int c2 = v * 4 + cc;
            float rr = 1.f / (1.f + expf(-(gin[0][c2] + gs[0][c2])));
            float zz = 1.f / (1.f + expf(-(gin[1][c2] + gs[1][c2])));
            float nn = tanhf(fmaf(rr, gs[2][c2], gin[2][c2]));
            hn[c2] = (1.f - zz) * nn + zz * hp[cc];
        }
    }
    #pragma unroll
    for (int v = 0; v < 4; ++v) {
        f4 o;
        #pragma unroll
        for (int cc = 0; cc < 4; ++cc) o[cc] = hn[v * 4 + cc];
        *(f4*)(hnew + (size_t)b * Hdim + j0g + v * 4) = o;
        if (hfin) *(f4*)(hfin + (size_t)b * Hdim + j0g + v * 4) = o;
    }
    // next-step A-pack (hi/lo), kb == nt for these 32 k-positions
    #pragma unroll
    for (int half = 0; half < 2; ++half) {
        f16x8 vh, vl;
        #pragma unroll
        for (int e = 0; e < 8; ++e) {
            float x = hn[half * 8 + e];
            _Float16 hh = (_Float16)x;
            vh[e] = hh;
            vl[e] = (_Float16)(x - (float)hh);
        }
        int q = jg * 2 + half;
        int lane2 = (b & 15) + 16 * q, mt = b >> 4;
        size_t off = (((size_t)mt * 64 + nt) * 64 + lane2) * 8;
        *(f16x8*)(nAh + off) = vh;
        *(f16x8*)(nAl + off) = vl;
    }
    // partial logits
    #pragma unroll
    for (int o = 0; o < Odim; ++o) {
        float pl = 0.f;
        #pragma unroll
        for (int cc = 0; cc < 16; ++cc)
            pl = fmaf(hn[cc], s_wout[o][jg * 16 + cc], pl);
        atomicAdd(&Llog[b * Odim + o], pl);
    }

    // ---- global completion counter ----
    __threadfence();
    __syncthreads();
    if (tid == 0) s_old = atomicAdd(lastc, 1);
    __syncthreads();
    if (s_old != 63) return;
    __threadfence();

    // ---- Phase C: argmax + log_softmax + topi + lp (+ zero Llog) ----
    if (tid < Bdim) {
        float l[Odim];
        #pragma unroll
        for (int o = 0; o < Odim; ++o) l[o] = Llog[tid * Odim + o] + b_out[o];
        float m = l[0]; int bi = 0;
        #pragma unroll
        for (int o = 1; o < Odim; ++o)
            if (l[o] > m) { m = l[o]; bi = o; }   // strict > = first max
        float ssum = 0.f;
        #pragma unroll
        for (int o = 0; o < Odim; ++o) ssum += expf(l[o] - m);
        float lse = m + logf(ssum);
        topi_out[tid] = bi;
        #pragma unroll
        for (int o = 0; o < Odim; ++o) {
            lp[((size_t)tid * Tdim + t) * Odim + o] = l[o] - lse;
            Llog[tid * Odim + o] = 0.f;    // ready for next step
        }
    }
}

// ---------------------------------------------------------------------------
extern "C" void kernel_launch(void* const* d_in, const int* in_sizes, int n_in,
                              void* d_out, int out_size, void* d_ws, size_t ws_size,
                              hipStream_t stream) {
    const float* enc_hidden = (const float*)d_in[1];
    const float* target     = (const float*)d_in[2];
    const float* W_ih       = (const float*)d_in[3];
    const float* W_hh       = (const float*)d_in[4];
    const float* b_ih       = (const float*)d_in[5];
    const float* b_hh       = (const float*)d_in[6];
    const float* W_out      = (const float*)d_in[7];
    const float* b_out      = (const float*)d_in[8];

    float* out  = (float*)d_out;
    float* lp   = out;
    float* hfin = out + (size_t)Bdim * Tdim * Odim;

    float* ws    = (float*)d_ws;
    float* hb0   = ws;                          // 524288 f32
    float* hb1   = hb0 + 524288;                // 524288
    float* Gt    = hb1 + 524288;                // 92160
    float* Cpart = Gt + 15 * G3;                // 6291456
    float* Llog  = Cpart + 4 * (size_t)Bdim * G3;  // 3584
    int*   topibuf = (int*)(Llog + Bdim * Odim);   // 512
    int*   cnt   = topibuf + 512;               // 512*64
    int*   lastc = cnt + Tdim * 64;             // 512
    _Float16* Ah0 = (_Float16*)(lastc + Tdim);
    _Float16* Al0 = Ah0 + (size_t)Bdim * Hdim;
    _Float16* Ah1 = Al0 + (size_t)Bdim * Hdim;
    _Float16* Al1 = Ah1 + (size_t)Bdim * Hdim;
    _Float16* Bh  = Al1 + (size_t)Bdim * Hdim;
    _Float16* Bl  = Bh + (size_t)G3 * Hdim;

    prep_gtable<<<(15 * G3 + 255) / 256, 256, 0, stream>>>(b_ih, W_ih, Gt);
    prep_Bpack<<<(G3 * 256) / 256, 256, 0, stream>>>(W_hh, Bh, Bl);
    prep_A0<<<(Bdim * 256) / 256, 256, 0, stream>>>(enc_hidden, Ah0, Al0);
    zero_misc<<<(Tdim * 64 + 255) / 256, 256, 0, stream>>>(cnt, lastc, Llog);

    for (int t = 0; t < Tdim; ++t) {
        const float* hprev = (t == 0) ? enc_hidden : ((t & 1) ? hb0 : hb1);
        float* hnew = (t & 1) ? hb1 : hb0;
        const _Float16* cAh = (t & 1) ? Ah1 : Ah0;
        const _Float16* cAl = (t & 1) ? Al1 : Al0;
        _Float16* wAh = (t & 1) ? Ah0 : Ah1;
        _Float16* wAl = (t & 1) ? Al0 : Al1;
        int* tin  = topibuf + ((t + 1) & 1) * 256;
        int* tout = topibuf + (t & 1) * 256;
        step_kernel<<<dim3(64, 4), 512, 0, stream>>>(
            cAh, cAl, Bh, Bl, Cpart, hprev, hnew, Gt, target, W_ih, b_ih, b_hh,
            W_out, b_out, wAh, wAl, tin, tout, lp,
            (t == Tdim - 1) ? hfin : nullptr, cnt + t * 64, lastc + t, Llog, t);
    }
}

// Round 5
// 19808.528 us; speedup vs baseline: 5.3479x; 5.3479x over previous
//
#include <hip/hip_runtime.h>
#include <math.h>

typedef float f4 __attribute__((ext_vector_type(4)));
typedef _Float16 f16x8 __attribute__((ext_vector_type(8)));
typedef int i4 __attribute__((ext_vector_type(4)));

#define Hdim 2048
#define Bdim 256
#define Tdim 512
#define Odim 14
#define G3   6144   // 3*Hdim

// ---------------------------------------------------------------------------
// Prep kernels (once per launch)
// ---------------------------------------------------------------------------

__global__ void prep_gtable(const float* __restrict__ b_ih,
                            const float* __restrict__ W_ih,
                            float* __restrict__ Gt) {
    int idx = blockIdx.x * 256 + threadIdx.x;
    if (idx >= 15 * G3) return;
    int c = idx / G3, row = idx % G3;
    float v = b_ih[row];
    if (c < Odim) v += W_ih[row * Odim + c];
    Gt[idx] = v;
}

__global__ void prep_gi0(const float* __restrict__ b_ih,
                         const float* __restrict__ W_ih,
                         const float* __restrict__ target,
                         float* __restrict__ gi0) {
    int idx = blockIdx.x * 256 + threadIdx.x;
    int b = idx / G3, row = idx % G3;
    const float* x0 = target + (size_t)b * (Tdim * Odim);
    float s = b_ih[row];
    #pragma unroll
    for (int c = 0; c < Odim; ++c)
        s = fmaf(fmaxf(x0[c], 0.f), W_ih[row * Odim + c], s);
    gi0[idx] = s;
}

// W_hh (6144x2048 f32) -> hi/lo fp16 frag-major: [nt][kb][lane][8]
// n = nt*16 + (lane&15), k = kb*32 + (lane>>4)*8 + j
__global__ void prep_Bpack(const float* __restrict__ W,
                           _Float16* __restrict__ Bh, _Float16* __restrict__ Bl) {
    int idx = blockIdx.x * 256 + threadIdx.x;  // 6144*256 threads
    int n = idx >> 8, kc = idx & 255;
    const float* src = W + (size_t)n * Hdim + kc * 8;
    int kb = kc >> 2, q = kc & 3;
    int lane = (n & 15) + 16 * q;
    int nt = n >> 4;
    f16x8 vh, vl;
    #pragma unroll
    for (int j = 0; j < 8; ++j) {
        float w = src[j];
        _Float16 h = (_Float16)w;
        vh[j] = h;
        vl[j] = (_Float16)(w - (float)h);
    }
    size_t off = (((size_t)nt * 64 + kb) * 64 + lane) * 8;
    *(f16x8*)(Bh + off) = vh;
    *(f16x8*)(Bl + off) = vl;
}

// enc_hidden (256x2048 f32) -> hi/lo fp16 frag-major: [mt][kb][lane][8]
__global__ void prep_A0(const float* __restrict__ h0,
                        _Float16* __restrict__ Ah, _Float16* __restrict__ Al) {
    int idx = blockIdx.x * 256 + threadIdx.x;  // 256*256 threads
    int m = idx >> 8, kc = idx & 255;
    const float* src = h0 + (size_t)m * Hdim + kc * 8;
    int kb = kc >> 2, q = kc & 3;
    int lane = (m & 15) + 16 * q;
    int mt = m >> 4;
    f16x8 vh, vl;
    #pragma unroll
    for (int j = 0; j < 8; ++j) {
        float w = src[j];
        _Float16 h = (_Float16)w;
        vh[j] = h;
        vl[j] = (_Float16)(w - (float)h);
    }
    size_t off = (((size_t)mt * 64 + kb) * 64 + lane) * 8;
    *(f16x8*)(Ah + off) = vh;
    *(f16x8*)(Al + off) = vl;
}

// ---------------------------------------------------------------------------
// Kernel 1: hi/lo fp16 MFMA GEMM  C[256 x 6144] = A[256x2048] * W[6144x2048]^T
// C = Ah*Wh + Ah*Wl + Al*Wh  (fp32-equivalent precision)
// grid (128 N-tiles of 48, 4 K-slices of 512); 256 thr = 4 waves.
// LDS 48 KB -> 2 wgs/CU -> 2 waves/SIMD (latency cover for A/B staging).
// Wave w: rows [w*64, w*64+64) x all 48 N of the tile (mf=4 x nf=3 frags).
// ---------------------------------------------------------------------------
__global__ __launch_bounds__(256, 2)
void gemm_step(const _Float16* __restrict__ Ah, const _Float16* __restrict__ Al,
               const _Float16* __restrict__ Bh, const _Float16* __restrict__ Bl,
               float* __restrict__ Cpart) {
    // [buf][ hi: 12 blk x 64 lane x 8 | lo: same ]  (blk = ntl*4 + kbl)
    __shared__ _Float16 sB[2][12288];

    const int tid = threadIdx.x;
    const int wave = tid >> 6, lane = tid & 63;
    const int nt0 = blockIdx.x * 3;
    const int kb0 = blockIdx.y * 16;   // 16 kb-blocks (512 k) per slice

    f4 acc[4][3];
    #pragma unroll
    for (int mf = 0; mf < 4; ++mf)
        #pragma unroll
        for (int nf = 0; nf < 3; ++nf) acc[mf][nf] = (f4)0.f;

    i4 rh[3], rl[3];

    // stage chunk 0 (4 kb-blocks, hi+lo)
    #pragma unroll
    for (int i = 0; i < 3; ++i) {
        int e = i * 256 + tid, blk = e >> 6, l = e & 63;
        int ntl = blk >> 2, kbl = blk & 3;
        size_t off = (((size_t)(nt0 + ntl) * 64) + kb0 + kbl) * 512 + l * 8;
        rh[i] = *(const i4*)(Bh + off);
        rl[i] = *(const i4*)(Bl + off);
    }
    #pragma unroll
    for (int i = 0; i < 3; ++i) {
        ((i4*)sB[0])[i * 256 + tid] = rh[i];
        ((i4*)sB[0])[768 + i * 256 + tid] = rl[i];
    }
    __syncthreads();

    for (int c = 0; c < 4; ++c) {
        const int buf = c & 1;
        if (c < 3) {  // register-prefetch chunk c+1
            #pragma unroll
            for (int i = 0; i < 3; ++i) {
                int e = i * 256 + tid, blk = e >> 6, l = e & 63;
                int ntl = blk >> 2, kbl = blk & 3;
                size_t off = (((size_t)(nt0 + ntl) * 64) + kb0 + (c + 1) * 4 + kbl) * 512 + l * 8;
                rh[i] = *(const i4*)(Bh + off);
                rl[i] = *(const i4*)(Bl + off);
            }
        }
        #pragma unroll
        for (int kbl = 0; kbl < 4; ++kbl) {
            const int kb = kb0 + c * 4 + kbl;
            f16x8 a_h[4], a_l[4], b_h[3], b_l[3];
            #pragma unroll
            for (int mf = 0; mf < 4; ++mf) {
                size_t off = (((size_t)(wave * 4 + mf) * 64 + kb) * 64 + lane) * 8;
                a_h[mf] = *(const f16x8*)(Ah + off);
                a_l[mf] = *(const f16x8*)(Al + off);
            }
            #pragma unroll
            for (int nf = 0; nf < 3; ++nf) {
                int base = (nf * 4 + kbl) * 512 + lane * 8;
                b_h[nf] = *(const f16x8*)(&sB[buf][base]);
                b_l[nf] = *(const f16x8*)(&sB[buf][6144 + base]);
            }
            #pragma unroll
            for (int mf = 0; mf < 4; ++mf)
                #pragma unroll
                for (int nf = 0; nf < 3; ++nf) {
                    acc[mf][nf] = __builtin_amdgcn_mfma_f32_16x16x32_f16(
                        a_h[mf], b_h[nf], acc[mf][nf], 0, 0, 0);
                    acc[mf][nf] = __builtin_amdgcn_mfma_f32_16x16x32_f16(
                        a_h[mf], b_l[nf], acc[mf][nf], 0, 0, 0);
                    acc[mf][nf] = __builtin_amdgcn_mfma_f32_16x16x32_f16(
                        a_l[mf], b_h[nf], acc[mf][nf], 0, 0, 0);
                }
        }
        if (c < 3) {  // store prefetched chunk into the other buffer
            #pragma unroll
            for (int i = 0; i < 3; ++i) {
                ((i4*)sB[buf ^ 1])[i * 256 + tid] = rh[i];
                ((i4*)sB[buf ^ 1])[768 + i * 256 + tid] = rl[i];
            }
            __syncthreads();
        }
    }

    // store partials: C/D frag: col(N)=lane&15, row(M)=(lane>>4)*4+q
    const size_t base = (size_t)blockIdx.y * 256 * G3;
    #pragma unroll
    for (int mf = 0; mf < 4; ++mf) {
        int mrow = wave * 64 + mf * 16 + (lane >> 4) * 4;
        #pragma unroll
        for (int nf = 0; nf < 3; ++nf) {
            int n = (nt0 + nf) * 16 + (lane & 15);
            #pragma unroll
            for (int q = 0; q < 4; ++q)
                Cpart[base + (size_t)(mrow + q) * G3 + n] = acc[mf][nf][q];
        }
    }
}

// ---------------------------------------------------------------------------
// Kernel 2: fused epilogue. grid 256 (wg = batch row b), 256 thr.
// Sums 4 K-partials + b_hh + gi (table via topi/alive), gates, writes h fp32
// + hi/lo fp16 A-pack, then logits/argmax/log_softmax/topi (+h_final).
// ---------------------------------------------------------------------------
__global__ __launch_bounds__(256)
void fused_out(const float* __restrict__ hprev, float* __restrict__ hnew,
               const float* __restrict__ Cpart, const float* __restrict__ Gt,
               const float* __restrict__ gi0, const float* __restrict__ b_hh,
               const float* __restrict__ W_out, const float* __restrict__ b_out,
               _Float16* __restrict__ Ah, _Float16* __restrict__ Al,
               const int* __restrict__ topi_in, int* __restrict__ topi_out,
               float* __restrict__ lp, float* __restrict__ hfin, int t) {
    const int b = blockIdx.x;
    const int tid = threadIdx.x;
    __shared__ __align__(16) float sh[Hdim];
    __shared__ float sl[16];
    __shared__ int s_sel;
    __shared__ unsigned long long s_m[4];

    if (t > 0) {
        int tp = topi_in[tid];
        unsigned long long m = __ballot(tp == (Odim - 1));
        if ((tid & 63) == 0) s_m[tid >> 6] = m;
        __syncthreads();
        if (tid == 0) {
            int bw = b >> 6, bl = b & 63;
            unsigned long long le =
                s_m[bw] & ((bl == 63) ? ~0ULL : ((1ULL << (bl + 1)) - 1ULL));
            bool dead = (le != 0ULL);
            for (int w = 0; w < bw; ++w) dead = dead || (s_m[w] != 0ULL);
            s_sel = dead ? Odim : topi_in[b];
        }
        __syncthreads();
    }
    const float* gp = (t == 0) ? (gi0 + (size_t)b * G3)
                               : (Gt + (size_t)s_sel * G3);

    const int j0 = tid * 8;
    float hn[8];
    {
        float gsum[3][8];
        #pragma unroll
        for (int g = 0; g < 3; ++g) {
            f4 s0 = *(const f4*)(b_hh + g * Hdim + j0);
            f4 s1 = *(const f4*)(b_hh + g * Hdim + j0 + 4);
            #pragma unroll
            for (int c = 0; c < 4; ++c) { gsum[g][c] = s0[c]; gsum[g][4 + c] = s1[c]; }
            #pragma unroll
            for (int ks = 0; ks < 4; ++ks) {
                const float* cp = Cpart + ((size_t)ks * Bdim + b) * G3 + g * Hdim + j0;
                f4 p0 = *(const f4*)cp;
                f4 p1 = *(const f4*)(cp + 4);
                #pragma unroll
                for (int c = 0; c < 4; ++c) { gsum[g][c] += p0[c]; gsum[g][4 + c] += p1[c]; }
            }
        }
        f4 hp0 = *(const f4*)(hprev + (size_t)b * Hdim + j0);
        f4 hp1 = *(const f4*)(hprev + (size_t)b * Hdim + j0 + 4);
        f4 gr0 = *(const f4*)(gp + j0),            gr1 = *(const f4*)(gp + j0 + 4);
        f4 gz0 = *(const f4*)(gp + Hdim + j0),     gz1 = *(const f4*)(gp + Hdim + j0 + 4);
        f4 gn0 = *(const f4*)(gp + 2 * Hdim + j0), gn1 = *(const f4*)(gp + 2 * Hdim + j0 + 4);
        #pragma unroll
        for (int c = 0; c < 8; ++c) {
            float gi_r = (c < 4) ? gr0[c] : gr1[c - 4];
            float gi_z = (c < 4) ? gz0[c] : gz1[c - 4];
            float gi_n = (c < 4) ? gn0[c] : gn1[c - 4];
            float hp   = (c < 4) ? hp0[c] : hp1[c - 4];
            float rr = 1.f / (1.f + expf(-(gi_r + gsum[0][c])));
            float zz = 1.f / (1.f + expf(-(gi_z + gsum[1][c])));
            float nn = tanhf(fmaf(rr, gsum[2][c], gi_n));
            hn[c] = (1.f - zz) * nn + zz * hp;
        }
    }
    f4 o0, o1;
    #pragma unroll
    for (int c = 0; c < 4; ++c) { o0[c] = hn[c]; o1[c] = hn[4 + c]; }
    *(f4*)(hnew + (size_t)b * Hdim + j0) = o0;
    *(f4*)(hnew + (size_t)b * Hdim + j0 + 4) = o1;
    {   // hi/lo fp16 A-pack: mt=b>>4, kb=tid>>2, q=tid&3, lane=(b&15)+16q
        f16x8 vh, vl;
        #pragma unroll
        for (int c = 0; c < 8; ++c) {
            _Float16 hh = (_Float16)hn[c];
            vh[c] = hh;
            vl[c] = (_Float16)(hn[c] - (float)hh);
        }
        int kb = tid >> 2, q = tid & 3;
        int lane = (b & 15) + 16 * q, mt = b >> 4;
        size_t off = (((size_t)mt * 64 + kb) * 64 + lane) * 8;
        *(f16x8*)(Ah + off) = vh;
        *(f16x8*)(Al + off) = vl;
    }
    *(f4*)(sh + j0) = o0;
    *(f4*)(sh + j0 + 4) = o1;
    __syncthreads();

    const int w = tid >> 6, l = tid & 63;
    for (int o = w; o < Odim; o += 4) {
        const float* wo = W_out + (size_t)o * Hdim;
        float s = 0.f;
        #pragma unroll
        for (int i = 0; i < 32; ++i)
            s = fmaf(sh[l + 64 * i], wo[l + 64 * i], s);
        #pragma unroll
        for (int off = 32; off >= 1; off >>= 1)
            s += __shfl_down(s, off);
        if (l == 0) sl[o] = s + b_out[o];
    }
    __syncthreads();
    if (tid == 0) {
        float m = sl[0]; int bi = 0;
        #pragma unroll
        for (int o = 1; o < Odim; ++o)
            if (sl[o] > m) { m = sl[o]; bi = o; }   // strict > = first max
        float ssum = 0.f;
        #pragma unroll
        for (int o = 0; o < Odim; ++o) ssum += expf(sl[o] - m);
        topi_out[b] = bi;
        sl[14] = m + logf(ssum);
    }
    __syncthreads();
    if (tid < Odim)
        lp[(size_t)b * (Tdim * Odim) + (size_t)t * Odim + tid] = sl[tid] - sl[14];
    if (hfin) {
        *(f4*)(hfin + (size_t)b * Hdim + j0) = o0;
        *(f4*)(hfin + (size_t)b * Hdim + j0 + 4) = o1;
    }
}

// ---------------------------------------------------------------------------
extern "C" void kernel_launch(void* const* d_in, const int* in_sizes, int n_in,
                              void* d_out, int out_size, void* d_ws, size_t ws_size,
                              hipStream_t stream) {
    const float* enc_hidden = (const float*)d_in[1];
    const float* target     = (const float*)d_in[2];
    const float* W_ih       = (const float*)d_in[3];
    const float* W_hh       = (const float*)d_in[4];
    const float* b_ih       = (const float*)d_in[5];
    const float* b_hh       = (const float*)d_in[6];
    const float* W_out      = (const float*)d_in[7];
    const float* b_out      = (const float*)d_in[8];

    float* out  = (float*)d_out;
    float* lp   = out;
    float* hfin = out + (size_t)Bdim * Tdim * Odim;

    float* ws    = (float*)d_ws;
    float* hb0   = ws;                        // 524288
    float* hb1   = hb0 + 524288;              // 524288
    float* Gt    = hb1 + 524288;              // 92160
    float* gi0   = Gt + 15 * G3;              // 1572864
    float* Cpart = gi0 + (size_t)Bdim * G3;   // 4*1572864
    _Float16* Ah = (_Float16*)(Cpart + 4 * (size_t)Bdim * G3);  // 524288 halves
    _Float16* Al = Ah + (size_t)Bdim * Hdim;                    // 524288
    _Float16* Bh = Al + (size_t)Bdim * Hdim;                    // 12582912
    _Float16* Bl = Bh + (size_t)G3 * Hdim;                      // 12582912
    int* topibuf = (int*)(Bl + (size_t)G3 * Hdim);              // 512 ints

    prep_gtable<<<(15 * G3 + 255) / 256, 256, 0, stream>>>(b_ih, W_ih, Gt);
    prep_gi0<<<(Bdim * G3) / 256, 256, 0, stream>>>(b_ih, W_ih, target, gi0);
    prep_Bpack<<<(G3 * 256) / 256, 256, 0, stream>>>(W_hh, Bh, Bl);
    prep_A0<<<(Bdim * 256) / 256, 256, 0, stream>>>(enc_hidden, Ah, Al);

    for (int t = 0; t < Tdim; ++t) {
        float* hnew = (t & 1) ? hb1 : hb0;
        const float* hprev = (t == 0) ? enc_hidden : ((t & 1) ? hb0 : hb1);
        int* tin  = topibuf + ((t + 1) & 1) * 256;
        int* tout = topibuf + (t & 1) * 256;
        gemm_step<<<dim3(128, 4), 256, 0, stream>>>(Ah, Al, Bh, Bl, Cpart);
        fused_out<<<256, 256, 0, stream>>>(hprev, hnew, Cpart, Gt, gi0, b_hh,
                                           W_out, b_out, Ah, Al, tin, tout, lp,
                                           (t == Tdim - 1) ? hfin : nullptr, t);
    }
}